// Round 8
// baseline (351.485 us; speedup 1.0000x reference)
//
#include <hip/hip_runtime.h>

// Local cost-volume correlation, fp32, DPP window sharing, max-TLP layout.
// out[b, dy*9+dx, h, w] = (1/256) sum_c in1[b,c,h,w] * in2[b,c,h+dy-4,w+dx-4]
//
// R11 design (from R4..R10 post-mortems: duration ∝ 1/resident-waves across
// ALL variants; per-wave duty only ~14% (L3-latency loads, L2 thrashed).
// 512-thread blocks pack at 1.45/3.375 of grid limit vs 256-thread at
// 2.7/3.375 -> the residency lever is MANY SMALL BLOCKS, not split-K):
//  - 256-thread blocks, 4 waves; wave = ONE row, 2 px/lane (float2 loads)
//  - per channel: 2 loads + 8 DPP (chained +-1 -> cols px-4..px+5) + 18 FMA
//    = ~28 VALU/channel, less DPP overhead than R4's 2-row layout
//  - one dy per block, full 256-channel loop per wave: NO split-K, NO LDS,
//    no reduction barriers; acc[2][9]=18 regs, total ~60 VGPR
//  - grid = 1728 blocks (8b x 24 bands x 9 dy) = 6912 waves = 6.75/SIMD
//    available; 256-thr packing ~80% -> ~21 waves/CU (~2x R8's 11.6)
//  - XCD swizzle: a tile's 9 dy-blocks share blockIdx%8 (L2/L3 reuse)
//  - launch_bounds(256,6): VGPR cap ~85, comfortably above the ~60 needed
//    (R5/R6 lesson: never let live regs exceed the cap)

#define CH 256
#define HH 96
#define WW 128
#define CS (HH * WW)

__device__ __forceinline__ float wshr1(float x) {  // lane i <- lane i-1
  union { float f; int i; } u, o;
  u.f = x;
  o.i = __builtin_amdgcn_update_dpp(0, u.i, 0x138, 0xF, 0xF, true);
  return o.f;
}
__device__ __forceinline__ float wshl1(float x) {  // lane i <- lane i+1
  union { float f; int i; } u, o;
  u.f = x;
  o.i = __builtin_amdgcn_update_dpp(0, u.i, 0x130, 0xF, 0xF, true);
  return o.f;
}

__global__ __launch_bounds__(256, 6) void corr_tlp(
    const float* __restrict__ in1, const float* __restrict__ in2,
    float* __restrict__ out)
{
  // ---- block decode, XCD-swizzled: tile's 9 dy-blocks share blockIdx%8 ----
  const int j    = blockIdx.x;          // grid = 1728
  const int xcd  = j & 7;
  const int s    = j >> 3;              // 0..215
  const int dy   = s % 9;
  const int tq   = s / 9;               // 0..23
  const int tile = tq * 8 + xcd;        // 0..191
  const int band = tile % 24;
  const int b    = tile / 24;
  const int dyo  = dy - 4;

  // ---- thread decode: 4 row-waves x 64 lanes x 2 px ----
  const int tid  = threadIdx.x;
  const int wv   = tid >> 6;
  const int lane = tid & 63;
  const int h    = band * 4 + wv;           // 0..95, always valid
  const int px   = lane << 1;               // 0..126
  const int r2   = h + dyo;                 // in2 row, may be OOB
  const bool rowok = (unsigned)r2 < (unsigned)HH;
  const int r2c  = r2 < 0 ? 0 : (r2 > HH - 1 ? HH - 1 : r2);

  const float* __restrict__ p1 = in1 + ((size_t)b * CH * HH + h)   * WW + px;
  const float* __restrict__ p2 = in2 + ((size_t)b * CH * HH + r2c) * WW + px;

  float acc[2][9];
#pragma unroll
  for (int p = 0; p < 2; ++p)
#pragma unroll
    for (int d = 0; d < 9; ++d) acc[p][d] = 0.f;

  // ---- channel loop: all 256 channels ----
#pragma unroll 2
  for (int c = 0; c < CH; ++c) {
    const float2 a = *(const float2*)p1;  p1 += CS;
    const float2 m = *(const float2*)p2;  p2 += CS;

    // w[0..9] = in2 cols px-4 .. px+5 via chained +-1 lane DPP
    float w[10];
    w[2] = wshr1(m.x);  w[3] = wshr1(m.y);   // px-2, px-1
    w[0] = wshr1(w[2]); w[1] = wshr1(w[3]);  // px-4, px-3
    w[4] = m.x;         w[5] = m.y;          // px,   px+1
    w[6] = wshl1(m.x);  w[7] = wshl1(m.y);   // px+2, px+3
    w[8] = wshl1(w[6]); w[9] = wshl1(w[7]);  // px+4, px+5

#pragma unroll
    for (int d = 0; d < 9; ++d) {
      acc[0][d] = fmaf(a.x, w[d],     acc[0][d]);   // col px   + d-4
      acc[1][d] = fmaf(a.y, w[d + 1], acc[1][d]);   // col px+1 + d-4
    }
  }

  // ---- epilogue: zero OOB (row+col, incl. DPP wave-edge wrap), store ----
  const float sc = 1.0f / (float)CH;
  float* po = out + (((size_t)b * 81 + dy * 9) * HH + h) * WW + px;
#pragma unroll
  for (int d = 0; d < 9; ++d) {
    float2 v;
    const int c0 = px + d - 4;         // in2 col for p=0
    const int c1 = px + 1 + d - 4;     // in2 col for p=1
    v.x = (rowok && (unsigned)c0 < (unsigned)WW) ? acc[0][d] * sc : 0.f;
    v.y = (rowok && (unsigned)c1 < (unsigned)WW) ? acc[1][d] * sc : 0.f;
    *(float2*)po = v;
    po += (size_t)CS;  // next dx plane
  }
}

extern "C" void kernel_launch(void* const* d_in, const int* in_sizes, int n_in,
                              void* d_out, int out_size, void* d_ws, size_t ws_size,
                              hipStream_t stream) {
  const float* in1 = (const float*)d_in[0];
  const float* in2 = (const float*)d_in[1];
  float* out = (float*)d_out;
  hipLaunchKernelGGL(corr_tlp, dim3(1728), dim3(256), 0, stream, in1, in2, out);
}